// Round 10
// baseline (101.989 us; speedup 1.0000x reference)
//
#include <hip/hip_runtime.h>
#include <hip/hip_bf16.h>
#include <math.h>

#define BB 4
#define HH 128
#define WW 128
#define CIN 64
#define COUT 64
#define KK 9
#define OMC 27
#define NPIX (BB * HH * WW)

typedef __attribute__((ext_vector_type(8))) short bf16x8;
typedef __attribute__((ext_vector_type(4))) float f32x4;

static __device__ __forceinline__ unsigned int pkcvt(float a, float b) {
    __hip_bfloat162 h = __float22bfloat162_rn(make_float2(a, b));
    return *reinterpret_cast<unsigned int*>(&h);
}

// ---------------------------------------------------------------------------
// Kernel 0: one-shot transform of wmain f32 [576 k][64 n] into bf16 MFMA
// B-frag-ready layout (16B/lane coalesced loads in the main kernel).
// ---------------------------------------------------------------------------
__global__ __launch_bounds__(64) void wb_transform(
    const float* __restrict__ wmain, uint4* __restrict__ wb)
{
    const int tid  = blockIdx.x * 64 + threadIdx.x;  // [0, 18*4*64)
    const int lane = tid & 63;
    const int nf   = (tid >> 6) & 3;
    const int ks   = tid >> 8;
    const int k0   = ks * 32 + ((lane >> 4) * 8);
    const int n    = nf * 16 + (lane & 15);
    uint4 q;
    q.x = pkcvt(wmain[(size_t)(k0 + 0) * COUT + n], wmain[(size_t)(k0 + 1) * COUT + n]);
    q.y = pkcvt(wmain[(size_t)(k0 + 2) * COUT + n], wmain[(size_t)(k0 + 3) * COUT + n]);
    q.z = pkcvt(wmain[(size_t)(k0 + 4) * COUT + n], wmain[(size_t)(k0 + 5) * COUT + n]);
    q.w = pkcvt(wmain[(size_t)(k0 + 6) * COUT + n], wmain[(size_t)(k0 + 7) * COUT + n]);
    wb[tid] = q;
}

// ---------------------------------------------------------------------------
// Kernel 1: offset/mask conv as bf16 MFMA implicit GEMM.  Epilogue fuses the
// deformable prep: j<18 -> absolute sampling coords, j>=18 -> sigmoid(mask).
// ---------------------------------------------------------------------------
__global__ __launch_bounds__(256) void offset_conv_mfma(
    const float* __restrict__ x,
    const float* __restrict__ wofs,
    const float* __restrict__ bofs,
    float* __restrict__ om)
{
    __shared__ char lds[16384 + 36864];
    char* xs = lds;
    char* ws = lds + 16384;

    const int tid  = threadIdx.x;
    const int lane = tid & 63;
    const int wv   = tid >> 6;
    const int bid = ((blockIdx.x & 7) << 6) + (blockIdx.x >> 3);  // XCD chunk
    const int b = bid >> 7;
    const int h = bid & (HH - 1);
    const float* xrow0 = x + (size_t)b * HH * WW * CIN;

    #pragma unroll
    for (int r = 0; r < 9; ++r) {
        const int t  = r;
        const int j  = (tid >> 3) & 31;
        const int c8 = tid & 7;
        uint4 q;
        if (j < OMC) {
            const float* wp = wofs + ((size_t)t * CIN + c8 * 8) * OMC + j;
            q.x = pkcvt(wp[0 * OMC], wp[1 * OMC]);
            q.y = pkcvt(wp[2 * OMC], wp[3 * OMC]);
            q.z = pkcvt(wp[4 * OMC], wp[5 * OMC]);
            q.w = pkcvt(wp[6 * OMC], wp[7 * OMC]);
        } else {
            q.x = q.y = q.z = q.w = 0u;
        }
        const int off = (((t * 32 + j) * 128) + c8 * 16) ^ ((j & 7) << 4);
        *(uint4*)(ws + off) = q;
    }

    f32x4 acc[2][2] = {};
    const int w0 = wv * 32;

    for (int ty = 0; ty < 3; ++ty) {
        const int hy = h - 1 + ty;
        const bool vrow = (hy >= 0) && (hy < HH);
        __syncthreads();
        if (vrow) {
            const float* src = xrow0 + (size_t)hy * WW * CIN;
            #pragma unroll
            for (int r = 0; r < 4; ++r) {
                const int ch = tid + 256 * r;
                const int c8 = ch & 7;
                const int w  = ch >> 3;
                const float* p = src + (size_t)w * CIN + c8 * 8;
                float4 a0 = *(const float4*)p;
                float4 a1 = *(const float4*)(p + 4);
                uint4 q;
                q.x = pkcvt(a0.x, a0.y);
                q.y = pkcvt(a0.z, a0.w);
                q.z = pkcvt(a1.x, a1.y);
                q.w = pkcvt(a1.z, a1.w);
                const int off = (w * 128 + c8 * 16) ^ ((w & 7) << 4);
                *(uint4*)(xs + off) = q;
            }
        }
        __syncthreads();
        if (!vrow) continue;

        #pragma unroll
        for (int tx = 0; tx < 3; ++tx) {
            const int t = ty * 3 + tx;
            #pragma unroll
            for (int ch2 = 0; ch2 < 2; ++ch2) {
                bf16x8 bfr[2];
                #pragma unroll
                for (int nf = 0; nf < 2; ++nf) {
                    const int j = nf * 16 + (lane & 15);
                    const int off = (((t * 32 + j) * 128) + ch2 * 64 + ((lane >> 4) * 16))
                                    ^ ((j & 7) << 4);
                    bfr[nf] = *(const bf16x8*)(ws + off);
                }
                bf16x8 afr[2];
                #pragma unroll
                for (int m = 0; m < 2; ++m) {
                    const int wp = w0 + m * 16 + (lane & 15) + tx - 1;
                    const bool vv = (wp >= 0) && (wp < WW);
                    const int wc = vv ? wp : 0;
                    const int off = (wc * 128 + ch2 * 64 + ((lane >> 4) * 16))
                                    ^ ((wc & 7) << 4);
                    bf16x8 a = *(const bf16x8*)(xs + off);
                    if (!vv) a = (bf16x8)(short)0;
                    afr[m] = a;
                }
                acc[0][0] = __builtin_amdgcn_mfma_f32_16x16x32_bf16(afr[0], bfr[0], acc[0][0], 0, 0, 0);
                acc[0][1] = __builtin_amdgcn_mfma_f32_16x16x32_bf16(afr[0], bfr[1], acc[0][1], 0, 0, 0);
                acc[1][0] = __builtin_amdgcn_mfma_f32_16x16x32_bf16(afr[1], bfr[0], acc[1][0], 0, 0, 0);
                acc[1][1] = __builtin_amdgcn_mfma_f32_16x16x32_bf16(afr[1], bfr[1], acc[1][1], 0, 0, 0);
            }
        }
    }

    const int pixbase = (b * HH + h) * WW;
    #pragma unroll
    for (int nf = 0; nf < 2; ++nf) {
        const int j = nf * 16 + (lane & 15);
        if (j >= OMC) continue;
        const float bb = bofs[j];
        #pragma unroll
        for (int m = 0; m < 2; ++m) {
            const int row0 = w0 + m * 16 + ((lane >> 4) * 4);
            #pragma unroll
            for (int r = 0; r < 4; ++r) {
                float val = acc[m][nf][r] + bb;
                const int wpix = row0 + r;
                if (j < 18) {
                    const int t = j >> 1;
                    if ((j & 1) == 0) val += (float)(h - 1 + t / 3);     // absolute py
                    else              val += (float)(wpix - 1 + t % 3);  // absolute px
                } else {
                    val = 1.0f / (1.0f + __expf(-val));                  // sigmoid(mask)
                }
                om[(size_t)(pixbase + wpix) * OMC + j] = val;
            }
        }
    }
}

// ---------------------------------------------------------------------------
// Kernel 2: deformable sampling + MFMA, A-fragment built DIRECTLY in
// registers with the MFMA lane mapping (no LDS tile at all).
// Block = 256 thr = 4 waves = 2 pairs; pair owns 16 px; wave kw owns the
// channel half [kw*32, +32) of all 9 taps (ks = t*2+kw).
// Lane L: pixel p = L&15, channels [kw*32 + (L>>4)*8, +8).
// Per tap: 2 broadcast LDS entry reads + 4 corners x 2 float4 loads
// (each pixel-corner 128B half-line covered by 4 lanes) + 32 FMA +
// 4 cvt_pk -> A-frag in regs -> 4 MFMA.  Full 9-tap unroll for cross-tap
// ILP.  Pair-reduce acc through LDS (overlaid on dead entries, 2 barriers).
// ---------------------------------------------------------------------------
#define TMB 32   // pixels per block

__global__ __launch_bounds__(256, 4) void dcn_main_mfma(
    const float* __restrict__ x,
    const uint4* __restrict__ wb,
    const float* __restrict__ bias,
    const float* __restrict__ om,
    float* __restrict__ out)
{
    __shared__ char shm[9216];
    float4* ent_w = (float4*)shm;            // 288 * 16 = 4608 B
    int4*   ent_o = (int4*)(shm + 4608);     // 288 * 16 = 4608 B

    const int tid  = threadIdx.x;
    const int lane = tid & 63;
    const int wv   = tid >> 6;
    const int pair = wv >> 1;
    const int kw   = wv & 1;                 // channel half
    const int bid  = ((blockIdx.x & 7) << 8) + (blockIdx.x >> 3);  // XCD chunk
    const int pix0 = bid * TMB;
    const int b    = pix0 >> 14;
    const float* xb = x + (size_t)b * HH * WW * CIN;

    // ---- precompute 288 (pixel,tap) entries ----
    for (int e = tid; e < 288; e += 256) {
        const int pr = e / 144;
        const int r  = e - pr * 144;
        const int px = r / 9;
        const int t  = r - px * 9;
        const float* omp = om + (size_t)(pix0 + pr * 16 + px) * OMC;
        const float py  = omp[2 * t];
        const float pxx = omp[2 * t + 1];
        const float mk  = omp[18 + t];

        const float fy = floorf(py), fx = floorf(pxx);
        const int y0 = (int)fy, x0 = (int)fx;
        const float wy1 = py - fy, wx1 = pxx - fx;
        const float wy0 = 1.0f - wy1, wx0 = 1.0f - wx1;
        const bool vy0 = (unsigned)y0 < (unsigned)HH;
        const bool vy1 = (unsigned)(y0 + 1) < (unsigned)HH;
        const bool vx0 = (unsigned)x0 < (unsigned)WW;
        const bool vx1 = (unsigned)(x0 + 1) < (unsigned)WW;
        float4 w4;
        w4.x = (vy0 && vx0) ? wy0 * wx0 * mk : 0.0f;
        w4.y = (vy0 && vx1) ? wy0 * wx1 * mk : 0.0f;
        w4.z = (vy1 && vx0) ? wy1 * wx0 * mk : 0.0f;
        w4.w = (vy1 && vx1) ? wy1 * wx1 * mk : 0.0f;
        const int yc0 = min(max(y0, 0), HH - 1);
        const int yc1 = min(max(y0 + 1, 0), HH - 1);
        const int xc0 = min(max(x0, 0), WW - 1);
        const int xc1 = min(max(x0 + 1, 0), WW - 1);
        int4 o4;
        o4.x = (yc0 * WW + xc0) * (CIN * 4);
        o4.y = (yc0 * WW + xc1) * (CIN * 4);
        o4.z = (yc1 * WW + xc0) * (CIN * 4);
        o4.w = (yc1 * WW + xc1) * (CIN * 4);
        ent_w[e] = w4;
        ent_o[e] = o4;
    }
    __syncthreads();

    const int p    = lane & 15;
    const int cb   = (lane >> 4) * 8;        // channel sub-base within half
    const char* xc = (const char*)xb + (size_t)(kw * 32 + cb) * 4;
    const int ebase = pair * 144 + p * 9;

    f32x4 acc[4] = {};

    #pragma unroll
    for (int t = 0; t < KK; ++t) {
        const float4 w4 = ent_w[ebase + t];
        const int4   o4 = ent_o[ebase + t];

        const float4 c0a = *(const float4*)(xc + o4.x);
        const float4 c0b = *(const float4*)(xc + o4.x + 16);
        const float4 c1a = *(const float4*)(xc + o4.y);
        const float4 c1b = *(const float4*)(xc + o4.y + 16);
        const float4 c2a = *(const float4*)(xc + o4.z);
        const float4 c2b = *(const float4*)(xc + o4.z + 16);
        const float4 c3a = *(const float4*)(xc + o4.w);
        const float4 c3b = *(const float4*)(xc + o4.w + 16);

        float s[8];
        #pragma unroll
        for (int j = 0; j < 4; ++j) {
            s[j]     = w4.x * ((const float*)&c0a)[j] + w4.y * ((const float*)&c1a)[j]
                     + w4.z * ((const float*)&c2a)[j] + w4.w * ((const float*)&c3a)[j];
            s[4 + j] = w4.x * ((const float*)&c0b)[j] + w4.y * ((const float*)&c1b)[j]
                     + w4.z * ((const float*)&c2b)[j] + w4.w * ((const float*)&c3b)[j];
        }

        uint4 aq;
        aq.x = pkcvt(s[0], s[1]);
        aq.y = pkcvt(s[2], s[3]);
        aq.z = pkcvt(s[4], s[5]);
        aq.w = pkcvt(s[6], s[7]);
        const bf16x8 a = *(const bf16x8*)&aq;

        const int ks = t * 2 + kw;
        const uint4* wb0 = wb + ks * 4 * 64 + lane;
        #pragma unroll
        for (int nf = 0; nf < 4; ++nf) {
            const bf16x8 bfr = *(const bf16x8*)(wb0 + nf * 64);
            acc[nf] = __builtin_amdgcn_mfma_f32_16x16x32_bf16(a, bfr, acc[nf], 0, 0, 0);
        }
    }

    // ---- pair reduction: overlay red buffer on the dead entry arrays ----
    __syncthreads();                      // all waves done with entries
    f32x4* red = (f32x4*)shm;             // 2 pairs x 4 nf x 64 lanes x 16B = 8192 B
    if (kw == 1) {
        #pragma unroll
        for (int nf = 0; nf < 4; ++nf) red[(pair * 4 + nf) * 64 + lane] = acc[nf];
    }
    __syncthreads();
    if (kw == 0) {
        #pragma unroll
        for (int nf = 0; nf < 4; ++nf) {
            const f32x4 o = red[(pair * 4 + nf) * 64 + lane];
            const int n  = nf * 16 + (lane & 15);
            const float bs = bias[n];
            const int m0 = pair * 16 + ((lane >> 4) * 4);
            #pragma unroll
            for (int r = 0; r < 4; ++r) {
                out[(size_t)(pix0 + m0 + r) * COUT + n] = acc[nf][r] + o[r] + bs;
            }
        }
    }
}

extern "C" void kernel_launch(void* const* d_in, const int* in_sizes, int n_in,
                              void* d_out, int out_size, void* d_ws, size_t ws_size,
                              hipStream_t stream)
{
    const float* x     = (const float*)d_in[0];
    const float* wmain = (const float*)d_in[1];
    const float* bias  = (const float*)d_in[2];
    const float* wofs  = (const float*)d_in[3];
    const float* bofs  = (const float*)d_in[4];
    float* out = (float*)d_out;
    float* om  = (float*)d_ws;                                    // 7077888 B
    uint4* wb  = (uint4*)((char*)d_ws + (size_t)NPIX * OMC * 4);  // +73728 B

    wb_transform<<<72, 64, 0, stream>>>(wmain, wb);
    offset_conv_mfma<<<BB * HH, 256, 0, stream>>>(x, wofs, bofs, om);
    dcn_main_mfma<<<NPIX / TMB, 256, 0, stream>>>(x, wb, bias, om, out);
}

// Round 12
// 56.313 us; speedup vs baseline: 1.8111x; 1.8111x over previous
//
#include <hip/hip_runtime.h>
#include <hip/hip_bf16.h>
#include <math.h>

#define BB 4
#define HH 128
#define WW 128
#define CIN 64
#define COUT 64
#define KK 9
#define OMC 27
#define NPIX (BB * HH * WW)

typedef __attribute__((ext_vector_type(8))) short bf16x8;
typedef __attribute__((ext_vector_type(4))) float f32x4;

static __device__ __forceinline__ unsigned int pkcvt(float a, float b) {
    __hip_bfloat162 h = __float22bfloat162_rn(make_float2(a, b));
    return *reinterpret_cast<unsigned int*>(&h);
}

// ---------------------------------------------------------------------------
// Kernel 0: one-shot transform of wmain f32 [576 k][64 n] into bf16 MFMA
// B-frag-ready layout (16B/lane coalesced loads in the main kernel).
// ---------------------------------------------------------------------------
__global__ __launch_bounds__(64) void wb_transform(
    const float* __restrict__ wmain, uint4* __restrict__ wb)
{
    const int tid  = blockIdx.x * 64 + threadIdx.x;  // [0, 18*4*64)
    const int lane = tid & 63;
    const int nf   = (tid >> 6) & 3;
    const int ks   = tid >> 8;
    const int k0   = ks * 32 + ((lane >> 4) * 8);
    const int n    = nf * 16 + (lane & 15);
    uint4 q;
    q.x = pkcvt(wmain[(size_t)(k0 + 0) * COUT + n], wmain[(size_t)(k0 + 1) * COUT + n]);
    q.y = pkcvt(wmain[(size_t)(k0 + 2) * COUT + n], wmain[(size_t)(k0 + 3) * COUT + n]);
    q.z = pkcvt(wmain[(size_t)(k0 + 4) * COUT + n], wmain[(size_t)(k0 + 5) * COUT + n]);
    q.w = pkcvt(wmain[(size_t)(k0 + 6) * COUT + n], wmain[(size_t)(k0 + 7) * COUT + n]);
    wb[tid] = q;
}

// ---------------------------------------------------------------------------
// Kernel 1: offset/mask conv as bf16 MFMA implicit GEMM.  Epilogue fuses the
// deformable prep: j<18 -> absolute sampling coords, j>=18 -> sigmoid(mask).
// ---------------------------------------------------------------------------
__global__ __launch_bounds__(256) void offset_conv_mfma(
    const float* __restrict__ x,
    const float* __restrict__ wofs,
    const float* __restrict__ bofs,
    float* __restrict__ om)
{
    __shared__ char lds[16384 + 36864];
    char* xs = lds;
    char* ws = lds + 16384;

    const int tid  = threadIdx.x;
    const int lane = tid & 63;
    const int wv   = tid >> 6;
    const int bid = ((blockIdx.x & 7) << 6) + (blockIdx.x >> 3);  // XCD chunk
    const int b = bid >> 7;
    const int h = bid & (HH - 1);
    const float* xrow0 = x + (size_t)b * HH * WW * CIN;

    #pragma unroll
    for (int r = 0; r < 9; ++r) {
        const int t  = r;
        const int j  = (tid >> 3) & 31;
        const int c8 = tid & 7;
        uint4 q;
        if (j < OMC) {
            const float* wp = wofs + ((size_t)t * CIN + c8 * 8) * OMC + j;
            q.x = pkcvt(wp[0 * OMC], wp[1 * OMC]);
            q.y = pkcvt(wp[2 * OMC], wp[3 * OMC]);
            q.z = pkcvt(wp[4 * OMC], wp[5 * OMC]);
            q.w = pkcvt(wp[6 * OMC], wp[7 * OMC]);
        } else {
            q.x = q.y = q.z = q.w = 0u;
        }
        const int off = (((t * 32 + j) * 128) + c8 * 16) ^ ((j & 7) << 4);
        *(uint4*)(ws + off) = q;
    }

    f32x4 acc[2][2] = {};
    const int w0 = wv * 32;

    for (int ty = 0; ty < 3; ++ty) {
        const int hy = h - 1 + ty;
        const bool vrow = (hy >= 0) && (hy < HH);
        __syncthreads();
        if (vrow) {
            const float* src = xrow0 + (size_t)hy * WW * CIN;
            #pragma unroll
            for (int r = 0; r < 4; ++r) {
                const int ch = tid + 256 * r;
                const int c8 = ch & 7;
                const int w  = ch >> 3;
                const float* p = src + (size_t)w * CIN + c8 * 8;
                float4 a0 = *(const float4*)p;
                float4 a1 = *(const float4*)(p + 4);
                uint4 q;
                q.x = pkcvt(a0.x, a0.y);
                q.y = pkcvt(a0.z, a0.w);
                q.z = pkcvt(a1.x, a1.y);
                q.w = pkcvt(a1.z, a1.w);
                const int off = (w * 128 + c8 * 16) ^ ((w & 7) << 4);
                *(uint4*)(xs + off) = q;
            }
        }
        __syncthreads();
        if (!vrow) continue;

        #pragma unroll
        for (int tx = 0; tx < 3; ++tx) {
            const int t = ty * 3 + tx;
            #pragma unroll
            for (int ch2 = 0; ch2 < 2; ++ch2) {
                bf16x8 bfr[2];
                #pragma unroll
                for (int nf = 0; nf < 2; ++nf) {
                    const int j = nf * 16 + (lane & 15);
                    const int off = (((t * 32 + j) * 128) + ch2 * 64 + ((lane >> 4) * 16))
                                    ^ ((j & 7) << 4);
                    bfr[nf] = *(const bf16x8*)(ws + off);
                }
                bf16x8 afr[2];
                #pragma unroll
                for (int m = 0; m < 2; ++m) {
                    const int wp = w0 + m * 16 + (lane & 15) + tx - 1;
                    const bool vv = (wp >= 0) && (wp < WW);
                    const int wc = vv ? wp : 0;
                    const int off = (wc * 128 + ch2 * 64 + ((lane >> 4) * 16))
                                    ^ ((wc & 7) << 4);
                    bf16x8 a = *(const bf16x8*)(xs + off);
                    if (!vv) a = (bf16x8)(short)0;
                    afr[m] = a;
                }
                acc[0][0] = __builtin_amdgcn_mfma_f32_16x16x32_bf16(afr[0], bfr[0], acc[0][0], 0, 0, 0);
                acc[0][1] = __builtin_amdgcn_mfma_f32_16x16x32_bf16(afr[0], bfr[1], acc[0][1], 0, 0, 0);
                acc[1][0] = __builtin_amdgcn_mfma_f32_16x16x32_bf16(afr[1], bfr[0], acc[1][0], 0, 0, 0);
                acc[1][1] = __builtin_amdgcn_mfma_f32_16x16x32_bf16(afr[1], bfr[1], acc[1][1], 0, 0, 0);
            }
        }
    }

    const int pixbase = (b * HH + h) * WW;
    #pragma unroll
    for (int nf = 0; nf < 2; ++nf) {
        const int j = nf * 16 + (lane & 15);
        if (j >= OMC) continue;
        const float bb = bofs[j];
        #pragma unroll
        for (int m = 0; m < 2; ++m) {
            const int row0 = w0 + m * 16 + ((lane >> 4) * 4);
            #pragma unroll
            for (int r = 0; r < 4; ++r) {
                float val = acc[m][nf][r] + bb;
                const int wpix = row0 + r;
                if (j < 18) {
                    const int t = j >> 1;
                    if ((j & 1) == 0) val += (float)(h - 1 + t / 3);     // absolute py
                    else              val += (float)(wpix - 1 + t % 3);  // absolute px
                } else {
                    val = 1.0f / (1.0f + __expf(-val));                  // sigmoid(mask)
                }
                om[(size_t)(pixbase + wpix) * OMC + j] = val;
            }
        }
    }
}

// ---------------------------------------------------------------------------
// Kernel 2: deformable sampling + MFMA.  R9 structure (entry precompute +
// wave-private LDS tile + channel-half K-split, coalesced 128B gathers)
// with SOFTWARE-PIPELINED gathers: tap t+1's 8 corner float4 loads are
// issued (into named slot-A/slot-B registers) BEFORE tap t's FMA/pack/
// ds_write/ds_read/MFMA consume phase, so HBM/L2 latency hides under
// compute.  Hand-unrolled 9-tap loop, 2 slots, all indices compile-time.
// (Macro var names put digits BEFORE the pasted slot letter: c01##S, not
// c##S##01 — `01.w` lexes as one pp-number and breaks token pasting.)
// ---------------------------------------------------------------------------
#define TMB 32   // pixels per block

__global__ __launch_bounds__(256, 4) void dcn_main_mfma(
    const float* __restrict__ x,
    const uint4* __restrict__ wb,
    const float* __restrict__ bias,
    const float* __restrict__ om,
    float* __restrict__ out)
{
    __shared__ char shm[9216 + 4096];
    float4* ent_w = (float4*)shm;            // 288 * 16 = 4608 B
    int4*   ent_o = (int4*)(shm + 4608);     // 288 * 16 = 4608 B
    char*   ts    = shm + 9216;              // 4 waves * 1024 B tiles

    const int tid  = threadIdx.x;
    const int lane = tid & 63;
    const int wv   = tid >> 6;
    const int pair = wv >> 1;
    const int kw   = wv & 1;                 // channel half
    const int bid  = ((blockIdx.x & 7) << 8) + (blockIdx.x >> 3);  // XCD chunk
    const int pix0 = bid * TMB;
    const int b    = pix0 >> 14;
    const float* xb = x + (size_t)b * HH * WW * CIN;

    // ---- precompute 288 (pixel,tap) entries ----
    for (int e = tid; e < 288; e += 256) {
        const int pr = e / 144;
        const int r  = e - pr * 144;
        const int px = r / 9;
        const int t  = r - px * 9;
        const float* omp = om + (size_t)(pix0 + pr * 16 + px) * OMC;
        const float py  = omp[2 * t];
        const float pxx = omp[2 * t + 1];
        const float mk  = omp[18 + t];

        const float fy = floorf(py), fx = floorf(pxx);
        const int y0 = (int)fy, x0 = (int)fx;
        const float wy1 = py - fy, wx1 = pxx - fx;
        const float wy0 = 1.0f - wy1, wx0 = 1.0f - wx1;
        const bool vy0 = (unsigned)y0 < (unsigned)HH;
        const bool vy1 = (unsigned)(y0 + 1) < (unsigned)HH;
        const bool vx0 = (unsigned)x0 < (unsigned)WW;
        const bool vx1 = (unsigned)(x0 + 1) < (unsigned)WW;
        float4 w4;
        w4.x = (vy0 && vx0) ? wy0 * wx0 * mk : 0.0f;
        w4.y = (vy0 && vx1) ? wy0 * wx1 * mk : 0.0f;
        w4.z = (vy1 && vx0) ? wy1 * wx0 * mk : 0.0f;
        w4.w = (vy1 && vx1) ? wy1 * wx1 * mk : 0.0f;
        const int yc0 = min(max(y0, 0), HH - 1);
        const int yc1 = min(max(y0 + 1, 0), HH - 1);
        const int xc0 = min(max(x0, 0), WW - 1);
        const int xc1 = min(max(x0 + 1, 0), WW - 1);
        int4 o4;
        o4.x = (yc0 * WW + xc0) * (CIN * 4);
        o4.y = (yc0 * WW + xc1) * (CIN * 4);
        o4.z = (yc1 * WW + xc0) * (CIN * 4);
        o4.w = (yc1 * WW + xc1) * (CIN * 4);
        ent_w[e] = w4;
        ent_o[e] = o4;
    }
    __syncthreads();

    char* tsw = ts + wv * 1024;
    const int plane = lane >> 3;                 // pixel sub-index (0..7)
    const int ch0   = (lane & 7) * 4;            // 4 channels per lane
    const char* xc  = (const char*)xb + (size_t)(kw * 32 + ch0) * 4;
    const int e0b = pair * 144 + plane * 9;      // entries for pixel plane
    const int e1b = pair * 144 + (8 + plane) * 9;

    // tile write offsets (constant per lane)
    const int px0 = plane, px1 = 8 + plane;
    const int woff0 = px0 * 64 + (((lane & 7) * 8) ^ ((px0 & 3) << 4));
    const int woff1 = px1 * 64 + (((lane & 7) * 8) ^ ((px1 & 3) << 4));
    const int arow  = lane & 15;
    const int aoff  = arow * 64 + ((((lane >> 4) * 16)) ^ ((arow & 3) << 4));

    f32x4 acc[4] = {};

#define ISSUE(S, t) {                                                         \
        w0##S = ent_w[e0b + (t)];                                             \
        w1##S = ent_w[e1b + (t)];                                             \
        const int4 oa = ent_o[e0b + (t)];                                     \
        const int4 ob = ent_o[e1b + (t)];                                     \
        c00##S = *(const float4*)(xc + oa.x);                                 \
        c01##S = *(const float4*)(xc + oa.y);                                 \
        c02##S = *(const float4*)(xc + oa.z);                                 \
        c03##S = *(const float4*)(xc + oa.w);                                 \
        c10##S = *(const float4*)(xc + ob.x);                                 \
        c11##S = *(const float4*)(xc + ob.y);                                 \
        c12##S = *(const float4*)(xc + ob.z);                                 \
        c13##S = *(const float4*)(xc + ob.w);                                 \
    }

#define CONSUME(S, t) {                                                       \
        {                                                                     \
            const float4 w4 = w0##S;                                          \
            const float s0 = w4.x*c00##S.x + w4.y*c01##S.x                    \
                           + w4.z*c02##S.x + w4.w*c03##S.x;                   \
            const float s1 = w4.x*c00##S.y + w4.y*c01##S.y                    \
                           + w4.z*c02##S.y + w4.w*c03##S.y;                   \
            const float s2 = w4.x*c00##S.z + w4.y*c01##S.z                    \
                           + w4.z*c02##S.z + w4.w*c03##S.z;                   \
            const float s3 = w4.x*c00##S.w + w4.y*c01##S.w                    \
                           + w4.z*c02##S.w + w4.w*c03##S.w;                   \
            uint2 pkd; pkd.x = pkcvt(s0, s1); pkd.y = pkcvt(s2, s3);          \
            *(uint2*)(tsw + woff0) = pkd;                                     \
        }                                                                     \
        {                                                                     \
            const float4 w4 = w1##S;                                          \
            const float s0 = w4.x*c10##S.x + w4.y*c11##S.x                    \
                           + w4.z*c12##S.x + w4.w*c13##S.x;                   \
            const float s1 = w4.x*c10##S.y + w4.y*c11##S.y                    \
                           + w4.z*c12##S.y + w4.w*c13##S.y;                   \
            const float s2 = w4.x*c10##S.z + w4.y*c11##S.z                    \
                           + w4.z*c12##S.z + w4.w*c13##S.z;                   \
            const float s3 = w4.x*c10##S.w + w4.y*c11##S.w                    \
                           + w4.z*c12##S.w + w4.w*c13##S.w;                   \
            uint2 pkd; pkd.x = pkcvt(s0, s1); pkd.y = pkcvt(s2, s3);          \
            *(uint2*)(tsw + woff1) = pkd;                                     \
        }                                                                     \
        {                                                                     \
            const bf16x8 a = *(const bf16x8*)(tsw + aoff);                    \
            const uint4* wb0 = wb + ((t) * 2 + kw) * 4 * 64 + lane;           \
            const bf16x8 b0 = *(const bf16x8*)(wb0 + 0 * 64);                 \
            const bf16x8 b1 = *(const bf16x8*)(wb0 + 1 * 64);                 \
            const bf16x8 b2 = *(const bf16x8*)(wb0 + 2 * 64);                 \
            const bf16x8 b3 = *(const bf16x8*)(wb0 + 3 * 64);                 \
            acc[0] = __builtin_amdgcn_mfma_f32_16x16x32_bf16(a, b0, acc[0], 0, 0, 0); \
            acc[1] = __builtin_amdgcn_mfma_f32_16x16x32_bf16(a, b1, acc[1], 0, 0, 0); \
            acc[2] = __builtin_amdgcn_mfma_f32_16x16x32_bf16(a, b2, acc[2], 0, 0, 0); \
            acc[3] = __builtin_amdgcn_mfma_f32_16x16x32_bf16(a, b3, acc[3], 0, 0, 0); \
        }                                                                     \
    }

    float4 w0A, w1A, c00A, c01A, c02A, c03A, c10A, c11A, c12A, c13A;
    float4 w0B, w1B, c00B, c01B, c02B, c03B, c10B, c11B, c12B, c13B;

    ISSUE(A, 0)
    ISSUE(B, 1) CONSUME(A, 0)
    ISSUE(A, 2) CONSUME(B, 1)
    ISSUE(B, 3) CONSUME(A, 2)
    ISSUE(A, 4) CONSUME(B, 3)
    ISSUE(B, 5) CONSUME(A, 4)
    ISSUE(A, 6) CONSUME(B, 5)
    ISSUE(B, 7) CONSUME(A, 6)
    ISSUE(A, 8) CONSUME(B, 7)
    CONSUME(A, 8)

#undef ISSUE
#undef CONSUME

    // ---- pair reduction: overlay red buffer on the dead entry arrays ----
    __syncthreads();                      // all waves done with entries/tiles
    f32x4* red = (f32x4*)shm;             // 2 pairs x 4 nf x 64 lanes x 16B
    if (kw == 1) {
        #pragma unroll
        for (int nf = 0; nf < 4; ++nf) red[(pair * 4 + nf) * 64 + lane] = acc[nf];
    }
    __syncthreads();
    if (kw == 0) {
        #pragma unroll
        for (int nf = 0; nf < 4; ++nf) {
            const f32x4 o = red[(pair * 4 + nf) * 64 + lane];
            const int n  = nf * 16 + (lane & 15);
            const float bs = bias[n];
            const int m0 = pair * 16 + ((lane >> 4) * 4);
            #pragma unroll
            for (int r = 0; r < 4; ++r) {
                out[(size_t)(pix0 + m0 + r) * COUT + n] = acc[nf][r] + o[r] + bs;
            }
        }
    }
}

extern "C" void kernel_launch(void* const* d_in, const int* in_sizes, int n_in,
                              void* d_out, int out_size, void* d_ws, size_t ws_size,
                              hipStream_t stream)
{
    const float* x     = (const float*)d_in[0];
    const float* wmain = (const float*)d_in[1];
    const float* bias  = (const float*)d_in[2];
    const float* wofs  = (const float*)d_in[3];
    const float* bofs  = (const float*)d_in[4];
    float* out = (float*)d_out;
    float* om  = (float*)d_ws;                                    // 7077888 B
    uint4* wb  = (uint4*)((char*)d_ws + (size_t)NPIX * OMC * 4);  // +73728 B

    wb_transform<<<72, 64, 0, stream>>>(wmain, wb);
    offset_conv_mfma<<<BB * HH, 256, 0, stream>>>(x, wofs, bofs, om);
    dcn_main_mfma<<<NPIX / TMB, 256, 0, stream>>>(x, wb, bias, om, out);
}

// Round 13
// 44.560 us; speedup vs baseline: 2.2888x; 1.2638x over previous
//
#include <hip/hip_runtime.h>
#include <hip/hip_bf16.h>
#include <math.h>

#define BB 4
#define HH 128
#define WW 128
#define CIN 64
#define COUT 64
#define KK 9
#define OMC 27
#define NPIX (BB * HH * WW)

typedef __attribute__((ext_vector_type(8))) short bf16x8;
typedef __attribute__((ext_vector_type(4))) float f32x4;

static __device__ __forceinline__ unsigned int pkcvt(float a, float b) {
    __hip_bfloat162 h = __float22bfloat162_rn(make_float2(a, b));
    return *reinterpret_cast<unsigned int*>(&h);
}

// ---------------------------------------------------------------------------
// Kernel 0: one-shot weight transforms.
//  tid < 4608:  wmain f32 [576 k][64 n] -> wb bf16 B-frags  [18 ks][4 nf][64]
//  else      :  wofs  f32 [9 t][64 c][27 j] -> wf bf16 B-frags [18 ks][2 nf][64]
//               (ks = t*2 + ch-half, j padded to 32 with zeros)
// ---------------------------------------------------------------------------
__global__ __launch_bounds__(64) void weight_transform(
    const float* __restrict__ wmain, const float* __restrict__ wofs,
    uint4* __restrict__ wb, uint4* __restrict__ wf)
{
    const int tg = blockIdx.x * 64 + threadIdx.x;
    if (tg < 4608) {
        const int lane = tg & 63;
        const int nf   = (tg >> 6) & 3;
        const int ks   = tg >> 8;
        const int k0   = ks * 32 + ((lane >> 4) * 8);
        const int n    = nf * 16 + (lane & 15);
        uint4 q;
        q.x = pkcvt(wmain[(size_t)(k0 + 0) * COUT + n], wmain[(size_t)(k0 + 1) * COUT + n]);
        q.y = pkcvt(wmain[(size_t)(k0 + 2) * COUT + n], wmain[(size_t)(k0 + 3) * COUT + n]);
        q.z = pkcvt(wmain[(size_t)(k0 + 4) * COUT + n], wmain[(size_t)(k0 + 5) * COUT + n]);
        q.w = pkcvt(wmain[(size_t)(k0 + 6) * COUT + n], wmain[(size_t)(k0 + 7) * COUT + n]);
        wb[tg] = q;
    } else {
        const int idx  = tg - 4608;            // [0, 2304)
        const int lane = idx & 63;
        const int frag = idx >> 6;             // [0, 36) = ks*2 + nf
        const int nf   = frag & 1;
        const int ks   = frag >> 1;
        const int t    = ks >> 1;
        const int kw   = ks & 1;
        const int j    = nf * 16 + (lane & 15);
        const int c0   = kw * 32 + ((lane >> 4) * 8);
        uint4 q;
        if (j < OMC) {
            const float* wp = wofs + ((size_t)t * CIN + c0) * OMC + j;
            q.x = pkcvt(wp[0 * OMC], wp[1 * OMC]);
            q.y = pkcvt(wp[2 * OMC], wp[3 * OMC]);
            q.z = pkcvt(wp[4 * OMC], wp[5 * OMC]);
            q.w = pkcvt(wp[6 * OMC], wp[7 * OMC]);
        } else {
            q.x = q.y = q.z = q.w = 0u;
        }
        wf[frag * 64 + lane] = q;
    }
}

// ---------------------------------------------------------------------------
// FUSED kernel: offset-conv GEMM + deformable sampling + main MFMA, one
// block per 32-pixel row chunk (no global om, no inter-kernel barrier).
// 4 waves = 2 pairs x (kw = channel half).
// Phase 0: stage x tile [3 rows][34 px][64 ch] bf16, XOR-swizzled, 0-padded.
// Phase 1: om GEMM (M=16/pair, N=32, ks=t*2+kw), B from wf (L2, coalesced);
//          pair-reduce via LDS; epilogue (bias, abs coords, sigmoid) -> om_s.
// Phase 2: per-(pixel,tap) entry precompute from om_s (weights+offsets).
// Phase 3: software-pipelined gather (2-slot issue-early/consume-late) +
//          wave-private LDS tile transpose + MFMA with wb  (= R12 loop).
// Phase 4: pair-reduce main acc, + bias, store.
// ---------------------------------------------------------------------------
#define TMB 32   // pixels per block

__global__ __launch_bounds__(256, 4) void dcn_fused(
    const float* __restrict__ x,
    const uint4* __restrict__ wb,
    const uint4* __restrict__ wf,
    const float* __restrict__ bias,
    const float* __restrict__ bofs,
    float* __restrict__ out)
{
    // xs 13056 | ent 9216 (overlaid: om_red 4096 / final red 8192) | om_s 3456 | ts 4096
    __shared__ char shm[13056 + 9216 + 3456 + 4096];
    char*   xs    = shm;
    float4* ent_w = (float4*)(shm + 13056);          // 288 * 16
    int4*   ent_o = (int4*)(shm + 13056 + 4608);     // 288 * 16
    float*  om_s  = (float*)(shm + 13056 + 9216);    // 32 * 27 f32
    char*   ts    = shm + 13056 + 9216 + 3456;       // 4 waves * 1024

    const int tid  = threadIdx.x;
    const int lane = tid & 63;
    const int wv   = tid >> 6;
    const int pair = wv >> 1;
    const int kw   = wv & 1;
    const int bid  = ((blockIdx.x & 7) << 8) + (blockIdx.x >> 3);  // XCD chunk
    const int pix0 = bid * TMB;
    const int b    = pix0 >> 14;
    const int h    = (pix0 >> 7) & (HH - 1);
    const int w0   = pix0 & (WW - 1);
    const float* xb = x + (size_t)b * HH * WW * CIN;

    // ---- phase 0: stage x tile [3][34][64] bf16, swizzled ----
    #pragma unroll
    for (int it = 0; it < 4; ++it) {
        const int idx = it * 256 + tid;
        if (idx < 816) {
            const int c8   = idx & 7;
            const int rest = idx >> 3;          // [0,102)
            const int ty   = rest / 34;
            const int wi   = rest - ty * 34;
            const int hy   = h - 1 + ty;
            const int wcol = w0 - 1 + wi;
            uint4 q;
            if ((unsigned)hy < (unsigned)HH && (unsigned)wcol < (unsigned)WW) {
                const float* p = xb + ((size_t)hy * WW + wcol) * CIN + c8 * 8;
                const float4 a0 = *(const float4*)p;
                const float4 a1 = *(const float4*)(p + 4);
                q.x = pkcvt(a0.x, a0.y);
                q.y = pkcvt(a0.z, a0.w);
                q.z = pkcvt(a1.x, a1.y);
                q.w = pkcvt(a1.z, a1.w);
            } else {
                q.x = q.y = q.z = q.w = 0u;
            }
            const int off = ((ty * 34 + wi) * 128 + c8 * 16) ^ ((wi & 7) << 4);
            *(uint4*)(xs + off) = q;
        }
    }
    __syncthreads();

    // ---- phase 1: om GEMM ----
    f32x4 accm[2] = {};
    #pragma unroll
    for (int t = 0; t < KK; ++t) {
        const int ty = t / 3, tx = t % 3;
        const int wi = pair * 16 + (lane & 15) + tx;
        const int aoff = ((ty * 34 + wi) * 128 + kw * 64 + ((lane >> 4) * 16))
                         ^ ((wi & 7) << 4);
        const bf16x8 a = *(const bf16x8*)(xs + aoff);
        const uint4* wf0 = wf + ((t * 2 + kw) * 2) * 64 + lane;
        const bf16x8 b0 = *(const bf16x8*)(wf0);
        const bf16x8 b1 = *(const bf16x8*)(wf0 + 64);
        accm[0] = __builtin_amdgcn_mfma_f32_16x16x32_bf16(a, b0, accm[0], 0, 0, 0);
        accm[1] = __builtin_amdgcn_mfma_f32_16x16x32_bf16(a, b1, accm[1], 0, 0, 0);
    }

    // pair-reduce om + epilogue -> om_s
    f32x4* om_red = (f32x4*)(shm + 13056);    // overlay on (not-yet-used) ent
    if (kw == 1) {
        om_red[(pair * 2 + 0) * 64 + lane] = accm[0];
        om_red[(pair * 2 + 1) * 64 + lane] = accm[1];
    }
    __syncthreads();
    if (kw == 0) {
        #pragma unroll
        for (int nf = 0; nf < 2; ++nf) {
            const int j = nf * 16 + (lane & 15);
            if (j >= OMC) continue;
            const f32x4 o = om_red[(pair * 2 + nf) * 64 + lane];
            const float bb = bofs[j];
            const int m0 = pair * 16 + ((lane >> 4) * 4);
            #pragma unroll
            for (int r = 0; r < 4; ++r) {
                float val = accm[nf][r] + o[r] + bb;
                const int wpix = w0 + m0 + r;
                if (j < 18) {
                    const int t = j >> 1;
                    if ((j & 1) == 0) val += (float)(h - 1 + t / 3);     // abs py
                    else              val += (float)(wpix - 1 + t % 3);  // abs px
                } else {
                    val = 1.0f / (1.0f + __expf(-val));                  // sigmoid
                }
                om_s[(m0 + r) * OMC + j] = val;
            }
        }
    }
    __syncthreads();

    // ---- phase 2: entry precompute from om_s ----
    for (int e = tid; e < 288; e += 256) {
        const int px = e / 9;
        const int t  = e - px * 9;
        const float py  = om_s[px * OMC + 2 * t];
        const float pxx = om_s[px * OMC + 2 * t + 1];
        const float mk  = om_s[px * OMC + 18 + t];

        const float fy = floorf(py), fx = floorf(pxx);
        const int y0 = (int)fy, x0 = (int)fx;
        const float wy1 = py - fy, wx1 = pxx - fx;
        const float wy0 = 1.0f - wy1, wx0 = 1.0f - wx1;
        const bool vy0 = (unsigned)y0 < (unsigned)HH;
        const bool vy1 = (unsigned)(y0 + 1) < (unsigned)HH;
        const bool vx0 = (unsigned)x0 < (unsigned)WW;
        const bool vx1 = (unsigned)(x0 + 1) < (unsigned)WW;
        float4 w4;
        w4.x = (vy0 && vx0) ? wy0 * wx0 * mk : 0.0f;
        w4.y = (vy0 && vx1) ? wy0 * wx1 * mk : 0.0f;
        w4.z = (vy1 && vx0) ? wy1 * wx0 * mk : 0.0f;
        w4.w = (vy1 && vx1) ? wy1 * wx1 * mk : 0.0f;
        const int yc0 = min(max(y0, 0), HH - 1);
        const int yc1 = min(max(y0 + 1, 0), HH - 1);
        const int xc0 = min(max(x0, 0), WW - 1);
        const int xc1 = min(max(x0 + 1, 0), WW - 1);
        int4 o4;
        o4.x = (yc0 * WW + xc0) * (CIN * 4);
        o4.y = (yc0 * WW + xc1) * (CIN * 4);
        o4.z = (yc1 * WW + xc0) * (CIN * 4);
        o4.w = (yc1 * WW + xc1) * (CIN * 4);
        ent_w[e] = w4;
        ent_o[e] = o4;
    }
    __syncthreads();

    // ---- phase 3: pipelined gather + tile + MFMA (R12 loop) ----
    char* tsw = ts + wv * 1024;
    const int plane = lane >> 3;
    const int ch0   = (lane & 7) * 4;
    const char* xc  = (const char*)xb + (size_t)(kw * 32 + ch0) * 4;
    const int e0b = pair * 144 + plane * 9;
    const int e1b = pair * 144 + (8 + plane) * 9;

    const int px0 = plane, px1 = 8 + plane;
    const int woff0 = px0 * 64 + (((lane & 7) * 8) ^ ((px0 & 3) << 4));
    const int woff1 = px1 * 64 + (((lane & 7) * 8) ^ ((px1 & 3) << 4));
    const int arow  = lane & 15;
    const int aoff  = arow * 64 + ((((lane >> 4) * 16)) ^ ((arow & 3) << 4));

    f32x4 acc[4] = {};

#define ISSUE(S, t) {                                                         \
        w0##S = ent_w[e0b + (t)];                                             \
        w1##S = ent_w[e1b + (t)];                                             \
        const int4 oa = ent_o[e0b + (t)];                                     \
        const int4 ob = ent_o[e1b + (t)];                                     \
        c00##S = *(const float4*)(xc + oa.x);                                 \
        c01##S = *(const float4*)(xc + oa.y);                                 \
        c02##S = *(const float4*)(xc + oa.z);                                 \
        c03##S = *(const float4*)(xc + oa.w);                                 \
        c10##S = *(const float4*)(xc + ob.x);                                 \
        c11##S = *(const float4*)(xc + ob.y);                                 \
        c12##S = *(const float4*)(xc + ob.z);                                 \
        c13##S = *(const float4*)(xc + ob.w);                                 \
    }

#define CONSUME(S, t) {                                                       \
        {                                                                     \
            const float4 w4 = w0##S;                                          \
            const float s0 = w4.x*c00##S.x + w4.y*c01##S.x                    \
                           + w4.z*c02##S.x + w4.w*c03##S.x;                   \
            const float s1 = w4.x*c00##S.y + w4.y*c01##S.y                    \
                           + w4.z*c02##S.y + w4.w*c03##S.y;                   \
            const float s2 = w4.x*c00##S.z + w4.y*c01##S.z                    \
                           + w4.z*c02##S.z + w4.w*c03##S.z;                   \
            const float s3 = w4.x*c00##S.w + w4.y*c01##S.w                    \
                           + w4.z*c02##S.w + w4.w*c03##S.w;                   \
            uint2 pkd; pkd.x = pkcvt(s0, s1); pkd.y = pkcvt(s2, s3);          \
            *(uint2*)(tsw + woff0) = pkd;                                     \
        }                                                                     \
        {                                                                     \
            const float4 w4 = w1##S;                                          \
            const float s0 = w4.x*c10##S.x + w4.y*c11##S.x                    \
                           + w4.z*c12##S.x + w4.w*c13##S.x;                   \
            const float s1 = w4.x*c10##S.y + w4.y*c11##S.y                    \
                           + w4.z*c12##S.y + w4.w*c13##S.y;                   \
            const float s2 = w4.x*c10##S.z + w4.y*c11##S.z                    \
                           + w4.z*c12##S.z + w4.w*c13##S.z;                   \
            const float s3 = w4.x*c10##S.w + w4.y*c11##S.w                    \
                           + w4.z*c12##S.w + w4.w*c13##S.w;                   \
            uint2 pkd; pkd.x = pkcvt(s0, s1); pkd.y = pkcvt(s2, s3);          \
            *(uint2*)(tsw + woff1) = pkd;                                     \
        }                                                                     \
        {                                                                     \
            const bf16x8 a = *(const bf16x8*)(tsw + aoff);                    \
            const uint4* wb0 = wb + ((t) * 2 + kw) * 4 * 64 + lane;           \
            const bf16x8 b0 = *(const bf16x8*)(wb0 + 0 * 64);                 \
            const bf16x8 b1 = *(const bf16x8*)(wb0 + 1 * 64);                 \
            const bf16x8 b2 = *(const bf16x8*)(wb0 + 2 * 64);                 \
            const bf16x8 b3 = *(const bf16x8*)(wb0 + 3 * 64);                 \
            acc[0] = __builtin_amdgcn_mfma_f32_16x16x32_bf16(a, b0, acc[0], 0, 0, 0); \
            acc[1] = __builtin_amdgcn_mfma_f32_16x16x32_bf16(a, b1, acc[1], 0, 0, 0); \
            acc[2] = __builtin_amdgcn_mfma_f32_16x16x32_bf16(a, b2, acc[2], 0, 0, 0); \
            acc[3] = __builtin_amdgcn_mfma_f32_16x16x32_bf16(a, b3, acc[3], 0, 0, 0); \
        }                                                                     \
    }

    float4 w0A, w1A, c00A, c01A, c02A, c03A, c10A, c11A, c12A, c13A;
    float4 w0B, w1B, c00B, c01B, c02B, c03B, c10B, c11B, c12B, c13B;

    ISSUE(A, 0)
    ISSUE(B, 1) CONSUME(A, 0)
    ISSUE(A, 2) CONSUME(B, 1)
    ISSUE(B, 3) CONSUME(A, 2)
    ISSUE(A, 4) CONSUME(B, 3)
    ISSUE(B, 5) CONSUME(A, 4)
    ISSUE(A, 6) CONSUME(B, 5)
    ISSUE(B, 7) CONSUME(A, 6)
    ISSUE(A, 8) CONSUME(B, 7)
    CONSUME(A, 8)

#undef ISSUE
#undef CONSUME

    // ---- phase 4: pair reduction (red overlaid on dead ent area) ----
    __syncthreads();
    f32x4* red = (f32x4*)(shm + 13056);
    if (kw == 1) {
        #pragma unroll
        for (int nf = 0; nf < 4; ++nf) red[(pair * 4 + nf) * 64 + lane] = acc[nf];
    }
    __syncthreads();
    if (kw == 0) {
        #pragma unroll
        for (int nf = 0; nf < 4; ++nf) {
            const f32x4 o = red[(pair * 4 + nf) * 64 + lane];
            const int n  = nf * 16 + (lane & 15);
            const float bs = bias[n];
            const int m0 = pair * 16 + ((lane >> 4) * 4);
            #pragma unroll
            for (int r = 0; r < 4; ++r) {
                out[(size_t)(pix0 + m0 + r) * COUT + n] = acc[nf][r] + o[r] + bs;
            }
        }
    }
}

extern "C" void kernel_launch(void* const* d_in, const int* in_sizes, int n_in,
                              void* d_out, int out_size, void* d_ws, size_t ws_size,
                              hipStream_t stream)
{
    const float* x     = (const float*)d_in[0];
    const float* wmain = (const float*)d_in[1];
    const float* bias  = (const float*)d_in[2];
    const float* wofs  = (const float*)d_in[3];
    const float* bofs  = (const float*)d_in[4];
    float* out = (float*)d_out;
    uint4* wb  = (uint4*)d_ws;                          // 73728 B
    uint4* wf  = (uint4*)((char*)d_ws + 73728);         // 36864 B

    weight_transform<<<108, 64, 0, stream>>>(wmain, wofs, wb, wf);
    dcn_fused<<<NPIX / TMB, 256, 0, stream>>>(x, wb, wf, bias, bofs, out);
}